// Round 12
// baseline (348.073 us; speedup 1.0000x reference)
//
#include <hip/hip_runtime.h>
#include <hip/hip_bf16.h>
#include <math.h>

typedef __bf16 bf16;
typedef __attribute__((ext_vector_type(8))) bf16 bf16x8;
typedef __attribute__((ext_vector_type(2))) bf16 bf16x2;
typedef __attribute__((ext_vector_type(16))) float f32x16;
typedef __attribute__((ext_vector_type(4))) unsigned int uint4v;

#define SQ 2048
#define DH 64
#define NH 16
#define KVT 32
#define NKVT (SQ / KVT)          // 64 tiles per bh
#define REC 8192                 // per-tile record: 4KB K-frags + 4KB V-frags
#define LOG2E 1.44269504088896340736f

__device__ __forceinline__ float fast_exp2(float x) {
#if __has_builtin(__builtin_amdgcn_exp2f)
    return __builtin_amdgcn_exp2f(x);
#else
    return exp2f(x);
#endif
}

__device__ __forceinline__ unsigned pkbf16(float a, float b) {
    union { bf16x2 h; unsigned u; } x;
    x.h = (bf16x2){(bf16)a, (bf16)b};
    return x.u;
}

// permlane32_swap: a' = [a.lo | b.lo], b' = [a.hi | b.hi]
#if __has_builtin(__builtin_amdgcn_permlane32_swap)
__device__ __forceinline__ void plswap(unsigned &a, unsigned &b) {
    typedef __attribute__((ext_vector_type(2))) unsigned int uint2v;
    uint2v r = __builtin_amdgcn_permlane32_swap(a, b, false, false);
    a = r[0]; b = r[1];
}
#else
__device__ __forceinline__ void plswap(unsigned &a, unsigned &b) {
    asm volatile("v_permlane32_swap_b32 %0, %1" : "+v"(a), "+v"(b));
}
#endif

union FragU { uint4v u; bf16x8 b; };

// ---------- prepass: write K and V as pre-fragmented 8KB tile records ----------
// Record for (bh, tile): kf[ds][lane] 16B = K[kv0+ (lane&31)][ds*16+(lane>>5)*8 ..+8]
//                        vf[g][lane]  16B = V[kv0+(g&1)*16+(lane>>5)*8 ..+8][(g>>1)*32+(lane&31)]
__global__ __launch_bounds__(256)
void alibi_prep_kernel(const float* __restrict__ K, const float* __restrict__ V,
                       char* __restrict__ W) {
    __shared__ bf16 lt[64][80];       // V transpose staging: lt[d][s_local]
    const int t  = threadIdx.x;
    const int s0 = blockIdx.x * 64;   // 64 kv rows = 2 tiles
    const int bh = blockIdx.y;
    if (blockIdx.z == 0) {
        // K -> fragment order (pure permutation, no transpose)
#pragma unroll
        for (int i = 0; i < 2; ++i) {
            const int g    = i * 256 + t;      // 0..511 chunks of 16B
            const int tile = g >> 8;
            const int cc   = g & 255;
            const int ds   = cc >> 6;
            const int lane = cc & 63;
            const float* p = K + ((size_t)bh * SQ + s0 + tile * 32 + (lane & 31)) * DH
                               + ds * 16 + (lane >> 5) * 8;
            float4 a = *(const float4*)p, b = *(const float4*)(p + 4);
            bf16x8 pk = {(bf16)a.x,(bf16)a.y,(bf16)a.z,(bf16)a.w,
                         (bf16)b.x,(bf16)b.y,(bf16)b.z,(bf16)b.w};
            *(bf16x8*)(W + (size_t)(bh * NKVT + (s0 >> 5) + tile) * REC
                         + ds * 1024 + lane * 16) = pk;
        }
    } else {
        // V -> LDS transpose -> fragment order
#pragma unroll
        for (int i = 0; i < 2; ++i) {
            int idx = i * 256 + t;
            int row = idx >> 3, c8 = idx & 7;
            const float* p = V + ((size_t)bh * SQ + s0 + row) * DH + c8 * 8;
            float4 a = *(const float4*)p, b = *(const float4*)(p + 4);
            bf16 e[8] = {(bf16)a.x,(bf16)a.y,(bf16)a.z,(bf16)a.w,
                         (bf16)b.x,(bf16)b.y,(bf16)b.z,(bf16)b.w};
#pragma unroll
            for (int jj = 0; jj < 8; ++jj) lt[c8 * 8 + jj][row] = e[jj];
        }
        __syncthreads();
#pragma unroll
        for (int i = 0; i < 2; ++i) {
            const int g    = i * 256 + t;
            const int tile = g >> 8;
            const int cc   = g & 255;
            const int grp  = cc >> 6;          // dblk*2 + ks
            const int lane = cc & 63;
            const int d    = (grp >> 1) * 32 + (lane & 31);
            const int sl   = tile * 32 + (grp & 1) * 16 + (lane >> 5) * 8;
            bf16x8 v = *(const bf16x8*)&lt[d][sl];
            *(bf16x8*)(W + (size_t)(bh * NKVT + (s0 >> 5) + tile) * REC
                         + 4096 + grp * 1024 + lane * 16) = v;
        }
    }
}

// ---------- main attention: no hot-loop LDS, 4-way kv parity, 32 waves/CU ----------
__global__ __launch_bounds__(256, 8)
void alibi_attn_kernel(const float* __restrict__ Q, const char* __restrict__ W,
                       float* __restrict__ Out) {
    __shared__ float ex[2][64][33];   // combine scratch: 2 slots (16.9 KB)
    const int tid  = threadIdx.x;
    const int lane = tid & 63;
    const int par  = tid >> 6;        // kv parity 0..3 (all 4 waves share (bh, q-chunk))
    const int r32  = lane & 31;
    const int hi   = lane >> 5;

    // ---- XCD-pinned mapping: XCD x owns heads {x, 15-x}, both batches ----
    const int B  = blockIdx.x;        // 0..2047
    const int x  = B & 7;
    const int j  = B >> 3;            // 0..255 within XCD
    const int sl = j >> 6;            // slot 0..3
    const int qc = j & 63;            // 32-row q-chunk
    const int h  = (sl < 2) ? (15 - x) : x;
    const int bh = (sl & 1) * NH + h;
    const int q0 = qc * 32;

    const float slope2  = exp2f(-0.5f * (float)(h + 1)) * LOG2E;
    const float SLOPE2N = -slope2;
    const float QSCALE  = 0.125f * LOG2E;

    // ---- ALiBi band (32-kv tiles): drop tiles with slope2*minDelta > 24 ----
    const int D = (int)(24.0f / slope2);
    const int a0 = q0 - D;
    const int tmin = (a0 <= 0) ? 0 : (a0 >> 5);
    const int tmax = min(NKVT - 1, (q0 + 31 + D) >> 5);

    const float* Qp = Q + (size_t)bh * SQ * DH;
    float*       Op = Out + (size_t)bh * SQ * DH;
    const char*  rec = W + (size_t)bh * NKVT * REC;

    // Q B-frag (pre-scaled): lane holds Q[q=qrow][ds*16 + hi*8 + j]
    const int qrow = q0 + r32;
    bf16x8 qfrag[4];
#pragma unroll
    for (int ds = 0; ds < 4; ++ds) {
        const float* sq = Qp + (size_t)qrow * DH + ds * 16 + hi * 8;
        float4 a = *(const float4*)sq, bb = *(const float4*)(sq + 4);
        qfrag[ds] = (bf16x8){(bf16)(a.x*QSCALE),(bf16)(a.y*QSCALE),
                             (bf16)(a.z*QSCALE),(bf16)(a.w*QSCALE),
                             (bf16)(bb.x*QSCALE),(bf16)(bb.y*QSCALE),
                             (bf16)(bb.z*QSCALE),(bf16)(bb.w*QSCALE)};
    }

    f32x16 oacc[2];
#pragma unroll
    for (int d = 0; d < 2; ++d)
#pragma unroll
        for (int rr = 0; rr < 16; ++rr) oacc[d][rr] = 0.f;
    float ps0 = 0.f, ps1 = 0.f, ps2 = 0.f, ps3 = 0.f;
    const float qh = (float)(qrow - 4 * hi);

    // ---- free-running band loop over my parity's tiles; no LDS, no barriers ----
    for (int t = tmin + par; t <= tmax; t += 4) {
        const char* rb = rec + (size_t)t * REC;

        bf16x8 kf[4], vf[4];
#pragma unroll
        for (int ds = 0; ds < 4; ++ds)
            kf[ds] = *(const bf16x8*)(rb + ds * 1024 + lane * 16);
#pragma unroll
        for (int g = 0; g < 4; ++g)
            vf[g] = *(const bf16x8*)(rb + 4096 + g * 1024 + lane * 16);

        // ---- S^T = K·Q^T : lane holds S^T[kv=(reg&3)+8*(reg>>2)+4hi][q=qrow] ----
        f32x16 sacc;
#pragma unroll
        for (int rr = 0; rr < 16; ++rr) sacc[rr] = 0.f;
        __builtin_amdgcn_s_setprio(1);
#pragma unroll
        for (int ds = 0; ds < 4; ++ds)
            sacc = __builtin_amdgcn_mfma_f32_32x32x16_bf16(kf[ds], qfrag[ds], sacc, 0, 0, 0);
        __builtin_amdgcn_s_setprio(0);

        // ---- softmax, no max-tracking: p = exp2(s + bias) ----
        const float gq = qh - (float)(t * KVT);
        float p[16];
#pragma unroll
        for (int reg = 0; reg < 16; ++reg) {
            const int krel = (reg & 3) + 8 * (reg >> 2);
            float d = gq - (float)krel;
            float s2 = fmaf(SLOPE2N, fabsf(d), sacc[reg]);
            float e = fast_exp2(s2);
            p[reg] = e;
            if ((reg & 3) == 0) ps0 += e;
            else if ((reg & 3) == 1) ps1 += e;
            else if ((reg & 3) == 2) ps2 += e;
            else ps3 += e;
        }

        // ---- PV: B-frag in-register (cvt_pk + permlane32_swap) ----
        __builtin_amdgcn_s_setprio(1);
#pragma unroll
        for (int ks = 0; ks < 2; ++ks) {
            unsigned u0 = pkbf16(p[8 * ks + 0], p[8 * ks + 1]);
            unsigned u1 = pkbf16(p[8 * ks + 2], p[8 * ks + 3]);
            unsigned v0 = pkbf16(p[8 * ks + 4], p[8 * ks + 5]);
            unsigned v1 = pkbf16(p[8 * ks + 6], p[8 * ks + 7]);
            plswap(u0, v0);
            plswap(u1, v1);
            FragU pf; pf.u = (uint4v){u0, u1, v0, v1};
#pragma unroll
            for (int dblk = 0; dblk < 2; ++dblk)
                oacc[dblk] = __builtin_amdgcn_mfma_f32_32x32x16_bf16(vf[dblk * 2 + ks], pf.b, oacc[dblk], 0, 0, 0);
        }
        __builtin_amdgcn_s_setprio(0);
    }

    // ---- combine 4 parities (tree via 2 LDS slots, 3 barriers) ----
    float psum = (ps0 + ps1) + (ps2 + ps3);
    psum += __shfl_xor(psum, 32);

    if (par & 1) {                    // par1 -> slot0, par3 -> slot1
        float* s = &ex[par >> 1][lane][0];
#pragma unroll
        for (int dblk = 0; dblk < 2; ++dblk)
#pragma unroll
            for (int g2 = 0; g2 < 4; ++g2)
                *(float4*)(s + dblk * 16 + g2 * 4) =
                    (float4){oacc[dblk][4*g2+0], oacc[dblk][4*g2+1],
                             oacc[dblk][4*g2+2], oacc[dblk][4*g2+3]};
        s[32] = psum;
    }
    __syncthreads();
    if (!(par & 1)) {                 // par0 += slot0, par2 += slot1
        const float* s = &ex[par >> 1][lane][0];
#pragma unroll
        for (int dblk = 0; dblk < 2; ++dblk)
#pragma unroll
            for (int g2 = 0; g2 < 4; ++g2) {
                float4 o = *(const float4*)(s + dblk * 16 + g2 * 4);
                oacc[dblk][4*g2+0] += o.x; oacc[dblk][4*g2+1] += o.y;
                oacc[dblk][4*g2+2] += o.z; oacc[dblk][4*g2+3] += o.w;
            }
        psum += s[32];
    }
    __syncthreads();
    if (par == 2) {                   // combined par2 -> slot0
        float* s = &ex[0][lane][0];
#pragma unroll
        for (int dblk = 0; dblk < 2; ++dblk)
#pragma unroll
            for (int g2 = 0; g2 < 4; ++g2)
                *(float4*)(s + dblk * 16 + g2 * 4) =
                    (float4){oacc[dblk][4*g2+0], oacc[dblk][4*g2+1],
                             oacc[dblk][4*g2+2], oacc[dblk][4*g2+3]};
        s[32] = psum;
    }
    __syncthreads();
    if (par == 0) {
        const float* s = &ex[0][lane][0];
#pragma unroll
        for (int dblk = 0; dblk < 2; ++dblk)
#pragma unroll
            for (int g2 = 0; g2 < 4; ++g2) {
                float4 o = *(const float4*)(s + dblk * 16 + g2 * 4);
                oacc[dblk][4*g2+0] += o.x; oacc[dblk][4*g2+1] += o.y;
                oacc[dblk][4*g2+2] += o.z; oacc[dblk][4*g2+3] += o.w;
            }
        psum += s[32];

        const float inv = 1.f / psum;
#pragma unroll
        for (int dblk = 0; dblk < 2; ++dblk)
#pragma unroll
            for (int g2 = 0; g2 < 4; ++g2) {
                float4 o = {oacc[dblk][4*g2+0] * inv, oacc[dblk][4*g2+1] * inv,
                            oacc[dblk][4*g2+2] * inv, oacc[dblk][4*g2+3] * inv};
                *(float4*)(Op + (size_t)qrow * DH + dblk * 32 + g2 * 8 + hi * 4) = o;
            }
    }
}

extern "C" void kernel_launch(void* const* d_in, const int* in_sizes, int n_in,
                              void* d_out, int out_size, void* d_ws, size_t ws_size,
                              hipStream_t stream) {
    const float* q = (const float*)d_in[0];
    const float* k = (const float*)d_in[1];
    const float* v = (const float*)d_in[2];
    float* out = (float*)d_out;
    char* W = (char*)d_ws;                    // 32 bh x 64 tiles x 8KB = 16 MB
    alibi_prep_kernel<<<dim3(SQ / 64, 2 * NH, 2), dim3(256), 0, stream>>>(k, v, W);
    const int nblk = 2 * NH * (SQ / 32);      // 2048 blocks (bh, 32-q-chunk)
    alibi_attn_kernel<<<dim3(nblk), dim3(256), 0, stream>>>(q, W, out);
}

// Round 13
// 48.833 us; speedup vs baseline: 7.1278x; 7.1278x over previous
//
#include <hip/hip_runtime.h>
#include <hip/hip_bf16.h>
#include <math.h>

typedef __bf16 bf16;
typedef __attribute__((ext_vector_type(8))) bf16 bf16x8;
typedef __attribute__((ext_vector_type(2))) bf16 bf16x2;
typedef __attribute__((ext_vector_type(16))) float f32x16;
typedef __attribute__((ext_vector_type(4))) unsigned int uint4v;

#define SQ 2048
#define DH 64
#define NH 16
#define KVT 32
#define NKVT (SQ / KVT)          // 64 tiles per bh
#define REC 8192                 // per-tile record: 4KB K-frags + 4KB V-frags
#define LOG2E 1.44269504088896340736f

__device__ __forceinline__ float fast_exp2(float x) {
#if __has_builtin(__builtin_amdgcn_exp2f)
    return __builtin_amdgcn_exp2f(x);
#else
    return exp2f(x);
#endif
}

__device__ __forceinline__ unsigned pkbf16(float a, float b) {
    union { bf16x2 h; unsigned u; } x;
    x.h = (bf16x2){(bf16)a, (bf16)b};
    return x.u;
}

// permlane32_swap: a' = [a.lo | b.lo], b' = [a.hi | b.hi]
#if __has_builtin(__builtin_amdgcn_permlane32_swap)
__device__ __forceinline__ void plswap(unsigned &a, unsigned &b) {
    typedef __attribute__((ext_vector_type(2))) unsigned int uint2v;
    uint2v r = __builtin_amdgcn_permlane32_swap(a, b, false, false);
    a = r[0]; b = r[1];
}
#else
__device__ __forceinline__ void plswap(unsigned &a, unsigned &b) {
    asm volatile("v_permlane32_swap_b32 %0, %1" : "+v"(a), "+v"(b));
}
#endif

union FragU { uint4v u; bf16x8 b; };

// ---------- prepass: write K and V as pre-fragmented 8KB tile records ----------
// Record for (bh, tile): kf[ds][lane] 16B = K[kv0+ (lane&31)][ds*16+(lane>>5)*8 ..+8]
//                        vf[g][lane]  16B = V[kv0+(g&1)*16+(lane>>5)*8 ..+8][(g>>1)*32+(lane&31)]
__global__ __launch_bounds__(256)
void alibi_prep_kernel(const float* __restrict__ K, const float* __restrict__ V,
                       char* __restrict__ W) {
    __shared__ bf16 lt[64][80];       // V transpose staging: lt[d][s_local]
    const int t  = threadIdx.x;
    const int s0 = blockIdx.x * 64;   // 64 kv rows = 2 tiles
    const int bh = blockIdx.y;
    if (blockIdx.z == 0) {
        // K -> fragment order (pure permutation, no transpose)
#pragma unroll
        for (int i = 0; i < 2; ++i) {
            const int g    = i * 256 + t;      // 0..511 chunks of 16B
            const int tile = g >> 8;
            const int cc   = g & 255;
            const int ds   = cc >> 6;
            const int lane = cc & 63;
            const float* p = K + ((size_t)bh * SQ + s0 + tile * 32 + (lane & 31)) * DH
                               + ds * 16 + (lane >> 5) * 8;
            float4 a = *(const float4*)p, b = *(const float4*)(p + 4);
            bf16x8 pk = {(bf16)a.x,(bf16)a.y,(bf16)a.z,(bf16)a.w,
                         (bf16)b.x,(bf16)b.y,(bf16)b.z,(bf16)b.w};
            *(bf16x8*)(W + (size_t)(bh * NKVT + (s0 >> 5) + tile) * REC
                         + ds * 1024 + lane * 16) = pk;
        }
    } else {
        // V -> LDS transpose -> fragment order
#pragma unroll
        for (int i = 0; i < 2; ++i) {
            int idx = i * 256 + t;
            int row = idx >> 3, c8 = idx & 7;
            const float* p = V + ((size_t)bh * SQ + s0 + row) * DH + c8 * 8;
            float4 a = *(const float4*)p, b = *(const float4*)(p + 4);
            bf16 e[8] = {(bf16)a.x,(bf16)a.y,(bf16)a.z,(bf16)a.w,
                         (bf16)b.x,(bf16)b.y,(bf16)b.z,(bf16)b.w};
#pragma unroll
            for (int jj = 0; jj < 8; ++jj) lt[c8 * 8 + jj][row] = e[jj];
        }
        __syncthreads();
#pragma unroll
        for (int i = 0; i < 2; ++i) {
            const int g    = i * 256 + t;
            const int tile = g >> 8;
            const int cc   = g & 255;
            const int grp  = cc >> 6;          // dblk*2 + ks
            const int lane = cc & 63;
            const int d    = (grp >> 1) * 32 + (lane & 31);
            const int sl   = tile * 32 + (grp & 1) * 16 + (lane >> 5) * 8;
            bf16x8 v = *(const bf16x8*)&lt[d][sl];
            *(bf16x8*)(W + (size_t)(bh * NKVT + (s0 >> 5) + tile) * REC
                         + 4096 + grp * 1024 + lane * 16) = v;
        }
    }
}

// ---------- main attention: no hot-loop LDS, 4-way kv parity ----------
// launch_bounds(256,4): 128-VGPR cap. (256,8) forced 64 and spilled ~1.4GB scratch (R12).
__global__ __launch_bounds__(256, 4)
void alibi_attn_kernel(const float* __restrict__ Q, const char* __restrict__ W,
                       float* __restrict__ Out) {
    __shared__ float ex[2][64][33];   // combine scratch: 2 slots (16.9 KB)
    const int tid  = threadIdx.x;
    const int lane = tid & 63;
    const int par  = tid >> 6;        // kv parity 0..3 (all 4 waves share (bh, q-chunk))
    const int r32  = lane & 31;
    const int hi   = lane >> 5;

    // ---- XCD-pinned mapping: XCD x owns heads {x, 15-x}, both batches ----
    const int B  = blockIdx.x;        // 0..2047
    const int x  = B & 7;
    const int j  = B >> 3;            // 0..255 within XCD
    const int sl = j >> 6;            // slot 0..3
    const int qc = j & 63;            // 32-row q-chunk
    const int h  = (sl < 2) ? (15 - x) : x;
    const int bh = (sl & 1) * NH + h;
    const int q0 = qc * 32;

    const float slope2  = exp2f(-0.5f * (float)(h + 1)) * LOG2E;
    const float SLOPE2N = -slope2;
    const float QSCALE  = 0.125f * LOG2E;

    // ---- ALiBi band (32-kv tiles): drop tiles with slope2*minDelta > 24 ----
    const int D = (int)(24.0f / slope2);
    const int a0 = q0 - D;
    const int tmin = (a0 <= 0) ? 0 : (a0 >> 5);
    const int tmax = min(NKVT - 1, (q0 + 31 + D) >> 5);

    const float* Qp = Q + (size_t)bh * SQ * DH;
    float*       Op = Out + (size_t)bh * SQ * DH;
    const char*  rec = W + (size_t)bh * NKVT * REC;

    // Q B-frag (pre-scaled): lane holds Q[q=qrow][ds*16 + hi*8 + j]
    const int qrow = q0 + r32;
    bf16x8 qfrag[4];
#pragma unroll
    for (int ds = 0; ds < 4; ++ds) {
        const float* sq = Qp + (size_t)qrow * DH + ds * 16 + hi * 8;
        float4 a = *(const float4*)sq, bb = *(const float4*)(sq + 4);
        qfrag[ds] = (bf16x8){(bf16)(a.x*QSCALE),(bf16)(a.y*QSCALE),
                             (bf16)(a.z*QSCALE),(bf16)(a.w*QSCALE),
                             (bf16)(bb.x*QSCALE),(bf16)(bb.y*QSCALE),
                             (bf16)(bb.z*QSCALE),(bf16)(bb.w*QSCALE)};
    }

    f32x16 oacc[2];
#pragma unroll
    for (int d = 0; d < 2; ++d)
#pragma unroll
        for (int rr = 0; rr < 16; ++rr) oacc[d][rr] = 0.f;
    float ps0 = 0.f, ps1 = 0.f, ps2 = 0.f, ps3 = 0.f;
    const float qh = (float)(qrow - 4 * hi);

    // ---- free-running band loop over my parity's tiles; no LDS, no barriers ----
    for (int t = tmin + par; t <= tmax; t += 4) {
        const char* rb = rec + (size_t)t * REC;

        bf16x8 kf[4], vf[4];
#pragma unroll
        for (int ds = 0; ds < 4; ++ds)
            kf[ds] = *(const bf16x8*)(rb + ds * 1024 + lane * 16);
#pragma unroll
        for (int g = 0; g < 4; ++g)
            vf[g] = *(const bf16x8*)(rb + 4096 + g * 1024 + lane * 16);

        // ---- S^T = K·Q^T : lane holds S^T[kv=(reg&3)+8*(reg>>2)+4hi][q=qrow] ----
        f32x16 sacc;
#pragma unroll
        for (int rr = 0; rr < 16; ++rr) sacc[rr] = 0.f;
        __builtin_amdgcn_s_setprio(1);
#pragma unroll
        for (int ds = 0; ds < 4; ++ds)
            sacc = __builtin_amdgcn_mfma_f32_32x32x16_bf16(kf[ds], qfrag[ds], sacc, 0, 0, 0);
        __builtin_amdgcn_s_setprio(0);

        // ---- softmax, no max-tracking: p = exp2(s + bias) ----
        const float gq = qh - (float)(t * KVT);
        float p[16];
#pragma unroll
        for (int reg = 0; reg < 16; ++reg) {
            const int krel = (reg & 3) + 8 * (reg >> 2);
            float d = gq - (float)krel;
            float s2 = fmaf(SLOPE2N, fabsf(d), sacc[reg]);
            float e = fast_exp2(s2);
            p[reg] = e;
            if ((reg & 3) == 0) ps0 += e;
            else if ((reg & 3) == 1) ps1 += e;
            else if ((reg & 3) == 2) ps2 += e;
            else ps3 += e;
        }

        // ---- PV: B-frag in-register (cvt_pk + permlane32_swap) ----
        __builtin_amdgcn_s_setprio(1);
#pragma unroll
        for (int ks = 0; ks < 2; ++ks) {
            unsigned u0 = pkbf16(p[8 * ks + 0], p[8 * ks + 1]);
            unsigned u1 = pkbf16(p[8 * ks + 2], p[8 * ks + 3]);
            unsigned v0 = pkbf16(p[8 * ks + 4], p[8 * ks + 5]);
            unsigned v1 = pkbf16(p[8 * ks + 6], p[8 * ks + 7]);
            plswap(u0, v0);
            plswap(u1, v1);
            FragU pf; pf.u = (uint4v){u0, u1, v0, v1};
#pragma unroll
            for (int dblk = 0; dblk < 2; ++dblk)
                oacc[dblk] = __builtin_amdgcn_mfma_f32_32x32x16_bf16(vf[dblk * 2 + ks], pf.b, oacc[dblk], 0, 0, 0);
        }
        __builtin_amdgcn_s_setprio(0);
    }

    // ---- combine 4 parities (tree via 2 LDS slots, 3 barriers) ----
    float psum = (ps0 + ps1) + (ps2 + ps3);
    psum += __shfl_xor(psum, 32);

    if (par & 1) {                    // par1 -> slot0, par3 -> slot1
        float* s = &ex[par >> 1][lane][0];
#pragma unroll
        for (int dblk = 0; dblk < 2; ++dblk)
#pragma unroll
            for (int g2 = 0; g2 < 4; ++g2)
                *(float4*)(s + dblk * 16 + g2 * 4) =
                    (float4){oacc[dblk][4*g2+0], oacc[dblk][4*g2+1],
                             oacc[dblk][4*g2+2], oacc[dblk][4*g2+3]};
        s[32] = psum;
    }
    __syncthreads();
    if (!(par & 1)) {                 // par0 += slot0, par2 += slot1
        const float* s = &ex[par >> 1][lane][0];
#pragma unroll
        for (int dblk = 0; dblk < 2; ++dblk)
#pragma unroll
            for (int g2 = 0; g2 < 4; ++g2) {
                float4 o = *(const float4*)(s + dblk * 16 + g2 * 4);
                oacc[dblk][4*g2+0] += o.x; oacc[dblk][4*g2+1] += o.y;
                oacc[dblk][4*g2+2] += o.z; oacc[dblk][4*g2+3] += o.w;
            }
        psum += s[32];
    }
    __syncthreads();
    if (par == 2) {                   // combined par2 -> slot0
        float* s = &ex[0][lane][0];
#pragma unroll
        for (int dblk = 0; dblk < 2; ++dblk)
#pragma unroll
            for (int g2 = 0; g2 < 4; ++g2)
                *(float4*)(s + dblk * 16 + g2 * 4) =
                    (float4){oacc[dblk][4*g2+0], oacc[dblk][4*g2+1],
                             oacc[dblk][4*g2+2], oacc[dblk][4*g2+3]};
        s[32] = psum;
    }
    __syncthreads();
    if (par == 0) {
        const float* s = &ex[0][lane][0];
#pragma unroll
        for (int dblk = 0; dblk < 2; ++dblk)
#pragma unroll
            for (int g2 = 0; g2 < 4; ++g2) {
                float4 o = *(const float4*)(s + dblk * 16 + g2 * 4);
                oacc[dblk][4*g2+0] += o.x; oacc[dblk][4*g2+1] += o.y;
                oacc[dblk][4*g2+2] += o.z; oacc[dblk][4*g2+3] += o.w;
            }
        psum += s[32];

        const float inv = 1.f / psum;
#pragma unroll
        for (int dblk = 0; dblk < 2; ++dblk)
#pragma unroll
            for (int g2 = 0; g2 < 4; ++g2) {
                float4 o = {oacc[dblk][4*g2+0] * inv, oacc[dblk][4*g2+1] * inv,
                            oacc[dblk][4*g2+2] * inv, oacc[dblk][4*g2+3] * inv};
                *(float4*)(Op + (size_t)qrow * DH + dblk * 32 + g2 * 8 + hi * 4) = o;
            }
    }
}

extern "C" void kernel_launch(void* const* d_in, const int* in_sizes, int n_in,
                              void* d_out, int out_size, void* d_ws, size_t ws_size,
                              hipStream_t stream) {
    const float* q = (const float*)d_in[0];
    const float* k = (const float*)d_in[1];
    const float* v = (const float*)d_in[2];
    float* out = (float*)d_out;
    char* W = (char*)d_ws;                    // 32 bh x 64 tiles x 8KB = 16 MB
    alibi_prep_kernel<<<dim3(SQ / 64, 2 * NH, 2), dim3(256), 0, stream>>>(k, v, W);
    const int nblk = 2 * NH * (SQ / 32);      // 2048 blocks (bh, 32-q-chunk)
    alibi_attn_kernel<<<dim3(nblk), dim3(256), 0, stream>>>(q, W, out);
}

// Round 14
// 46.652 us; speedup vs baseline: 7.4611x; 1.0468x over previous
//
#include <hip/hip_runtime.h>
#include <hip/hip_bf16.h>
#include <math.h>

typedef __bf16 bf16;
typedef __attribute__((ext_vector_type(8))) bf16 bf16x8;
typedef __attribute__((ext_vector_type(2))) bf16 bf16x2;
typedef __attribute__((ext_vector_type(16))) float f32x16;
typedef __attribute__((ext_vector_type(4))) unsigned int uint4v;

#define SQ 2048
#define DH 64
#define NH 16
#define KVT 32
#define NKVT (SQ / KVT)          // 64 tiles per bh
#define REC 8192                 // per-tile record: 4KB K-frags + 4KB V-frags
#define LOG2E 1.44269504088896340736f

__device__ __forceinline__ float fast_exp2(float x) {
#if __has_builtin(__builtin_amdgcn_exp2f)
    return __builtin_amdgcn_exp2f(x);
#else
    return exp2f(x);
#endif
}

__device__ __forceinline__ unsigned pkbf16(float a, float b) {
    union { bf16x2 h; unsigned u; } x;
    x.h = (bf16x2){(bf16)a, (bf16)b};
    return x.u;
}

#if __has_builtin(__builtin_amdgcn_permlane32_swap)
__device__ __forceinline__ void plswap(unsigned &a, unsigned &b) {
    typedef __attribute__((ext_vector_type(2))) unsigned int uint2v;
    uint2v r = __builtin_amdgcn_permlane32_swap(a, b, false, false);
    a = r[0]; b = r[1];
}
#else
__device__ __forceinline__ void plswap(unsigned &a, unsigned &b) {
    asm volatile("v_permlane32_swap_b32 %0, %1" : "+v"(a), "+v"(b));
}
#endif

union FragU { uint4v u; bf16x8 b; };

// ---------- prepass: write K and V as pre-fragmented 8KB tile records ----------
__global__ __launch_bounds__(256)
void alibi_prep_kernel(const float* __restrict__ K, const float* __restrict__ V,
                       char* __restrict__ W) {
    __shared__ bf16 lt[64][80];
    const int t  = threadIdx.x;
    const int s0 = blockIdx.x * 64;   // 64 kv rows = 2 tiles
    const int bh = blockIdx.y;
    if (blockIdx.z == 0) {
#pragma unroll
        for (int i = 0; i < 2; ++i) {
            const int g    = i * 256 + t;
            const int tile = g >> 8;
            const int cc   = g & 255;
            const int ds   = cc >> 6;
            const int lane = cc & 63;
            const float* p = K + ((size_t)bh * SQ + s0 + tile * 32 + (lane & 31)) * DH
                               + ds * 16 + (lane >> 5) * 8;
            float4 a = *(const float4*)p, b = *(const float4*)(p + 4);
            bf16x8 pk = {(bf16)a.x,(bf16)a.y,(bf16)a.z,(bf16)a.w,
                         (bf16)b.x,(bf16)b.y,(bf16)b.z,(bf16)b.w};
            *(bf16x8*)(W + (size_t)(bh * NKVT + (s0 >> 5) + tile) * REC
                         + ds * 1024 + lane * 16) = pk;
        }
    } else {
#pragma unroll
        for (int i = 0; i < 2; ++i) {
            int idx = i * 256 + t;
            int row = idx >> 3, c8 = idx & 7;
            const float* p = V + ((size_t)bh * SQ + s0 + row) * DH + c8 * 8;
            float4 a = *(const float4*)p, b = *(const float4*)(p + 4);
            bf16 e[8] = {(bf16)a.x,(bf16)a.y,(bf16)a.z,(bf16)a.w,
                         (bf16)b.x,(bf16)b.y,(bf16)b.z,(bf16)b.w};
#pragma unroll
            for (int jj = 0; jj < 8; ++jj) lt[c8 * 8 + jj][row] = e[jj];
        }
        __syncthreads();
#pragma unroll
        for (int i = 0; i < 2; ++i) {
            const int g    = i * 256 + t;
            const int tile = g >> 8;
            const int cc   = g & 255;
            const int grp  = cc >> 6;
            const int lane = cc & 63;
            const int d    = (grp >> 1) * 32 + (lane & 31);
            const int sv   = tile * 32 + (grp & 1) * 16 + (lane >> 5) * 8;
            bf16x8 v = *(const bf16x8*)&lt[d][sv];
            *(bf16x8*)(W + (size_t)(bh * NKVT + (s0 >> 5) + tile) * REC
                         + 4096 + grp * 1024 + lane * 16) = v;
        }
    }
}

// ---------- main attention: 64 q-rows/wave, 2-deep reg pipeline, no hot-loop LDS ----------
__global__ __launch_bounds__(256, 2)
void alibi_attn_kernel(const float* __restrict__ Q, const char* __restrict__ W,
                       float* __restrict__ Out) {
    __shared__ float ex[2][64][72];   // combine scratch (36.9 KB), epilogue only
    const int tid  = threadIdx.x;
    const int lane = tid & 63;
    const int par  = tid >> 6;        // kv parity 0..3
    const int r32  = lane & 31;
    const int hi   = lane >> 5;

    // ---- balanced XCD quadruples: XCD pair x>>1 = hs owns heads
    //      {15-hs, 11-hs, 2hs+1, 2hs}; batch = x&1. Work max/mean ~1.08. ----
    const int B   = blockIdx.x;       // 0..1023
    const int x   = B & 7;
    const int j   = B >> 3;           // 0..127
    const int sl  = j >> 5;           // 0..3
    const int qcr = j & 31;
    const int qc  = (qcr + sl * 8) & 31;   // rotate to decorrelate band clipping
    const int hs  = x >> 1;
    const int h   = (sl == 0) ? (15 - hs) : (sl == 1) ? (11 - hs)
                  : (sl == 2) ? (2 * hs + 1) : (2 * hs);
    const int bh  = (x & 1) * NH + h;
    const int q0  = qc * 64;

    const float slope2  = exp2f(-0.5f * (float)(h + 1)) * LOG2E;
    const float SLOPE2N = -slope2;
    const float QSCALE  = 0.125f * LOG2E;

    // ---- ALiBi band over 32-kv tiles for q in [q0, q0+64) ----
    const int D = (int)(24.0f / slope2);
    const int a0 = q0 - D;
    const int tmin = (a0 <= 0) ? 0 : (a0 >> 5);
    const int tmax = min(NKVT - 1, (q0 + 63 + D) >> 5);

    const float* Qp = Q + (size_t)bh * SQ * DH;
    float*       Op = Out + (size_t)bh * SQ * DH;
    const char*  rec = W + (size_t)bh * NKVT * REC;

    // Q fragments, two q-sets: A rows q0+r32, B rows q0+32+r32
    const int qrowA = q0 + r32;
    bf16x8 qfragA[4], qfragB[4];
#pragma unroll
    for (int ds = 0; ds < 4; ++ds) {
        const float* sa = Qp + (size_t)qrowA * DH + ds * 16 + hi * 8;
        float4 a = *(const float4*)sa, b = *(const float4*)(sa + 4);
        qfragA[ds] = (bf16x8){(bf16)(a.x*QSCALE),(bf16)(a.y*QSCALE),
                              (bf16)(a.z*QSCALE),(bf16)(a.w*QSCALE),
                              (bf16)(b.x*QSCALE),(bf16)(b.y*QSCALE),
                              (bf16)(b.z*QSCALE),(bf16)(b.w*QSCALE)};
        const float* sb = sa + 32 * DH;
        float4 c = *(const float4*)sb, d = *(const float4*)(sb + 4);
        qfragB[ds] = (bf16x8){(bf16)(c.x*QSCALE),(bf16)(c.y*QSCALE),
                              (bf16)(c.z*QSCALE),(bf16)(c.w*QSCALE),
                              (bf16)(d.x*QSCALE),(bf16)(d.y*QSCALE),
                              (bf16)(d.z*QSCALE),(bf16)(d.w*QSCALE)};
    }

    f32x16 oaccA[2], oaccB[2];
#pragma unroll
    for (int d2 = 0; d2 < 2; ++d2)
#pragma unroll
        for (int rr = 0; rr < 16; ++rr) { oaccA[d2][rr] = 0.f; oaccB[d2][rr] = 0.f; }
    float psA[4] = {0.f,0.f,0.f,0.f}, psB[4] = {0.f,0.f,0.f,0.f};
    const float qhA = (float)(qrowA - 4 * hi);

    auto LOADF = [&](bf16x8* kf, bf16x8* vf, int tt) {
        const char* rb = rec + (size_t)tt * REC + lane * 16;
#pragma unroll
        for (int ds = 0; ds < 4; ++ds) kf[ds] = *(const bf16x8*)(rb + ds * 1024);
#pragma unroll
        for (int g = 0; g < 4; ++g)    vf[g] = *(const bf16x8*)(rb + 4096 + g * 1024);
    };

    auto COMPUTE = [&](const bf16x8* kf, const bf16x8* vf, int tt) {
        const float gq0 = qhA - (float)(tt * KVT);
#pragma unroll
        for (int qs = 0; qs < 2; ++qs) {
            const bf16x8* qf = qs ? qfragB : qfragA;
            f32x16*       oa = qs ? oaccB  : oaccA;
            float*        ps = qs ? psB    : psA;
            const float   gq = qs ? gq0 + 32.f : gq0;

            f32x16 sacc;
#pragma unroll
            for (int rr = 0; rr < 16; ++rr) sacc[rr] = 0.f;
            __builtin_amdgcn_s_setprio(1);
#pragma unroll
            for (int ds = 0; ds < 4; ++ds)
                sacc = __builtin_amdgcn_mfma_f32_32x32x16_bf16(kf[ds], qf[ds], sacc, 0, 0, 0);
            __builtin_amdgcn_s_setprio(0);

            float p[16];
#pragma unroll
            for (int reg = 0; reg < 16; ++reg) {
                const int krel = (reg & 3) + 8 * (reg >> 2);
                float d = gq - (float)krel;
                float s2 = fmaf(SLOPE2N, fabsf(d), sacc[reg]);
                float e = fast_exp2(s2);
                p[reg] = e;
                ps[reg & 3] += e;
            }

            __builtin_amdgcn_s_setprio(1);
#pragma unroll
            for (int ks = 0; ks < 2; ++ks) {
                unsigned u0 = pkbf16(p[8 * ks + 0], p[8 * ks + 1]);
                unsigned u1 = pkbf16(p[8 * ks + 2], p[8 * ks + 3]);
                unsigned v0 = pkbf16(p[8 * ks + 4], p[8 * ks + 5]);
                unsigned v1 = pkbf16(p[8 * ks + 6], p[8 * ks + 7]);
                plswap(u0, v0);
                plswap(u1, v1);
                FragU pf; pf.u = (uint4v){u0, u1, v0, v1};
#pragma unroll
                for (int dblk = 0; dblk < 2; ++dblk)
                    oa[dblk] = __builtin_amdgcn_mfma_f32_32x32x16_bf16(vf[dblk * 2 + ks], pf.b, oa[dblk], 0, 0, 0);
            }
            __builtin_amdgcn_s_setprio(0);
        }
    };

    // ---- 2-deep software pipeline over my parity's tiles ----
    {
        bf16x8 kA[4], vA[4], kB[4], vB[4];
        int t = tmin + par;
        if (t <= tmax) {
            const int n = ((tmax - t) >> 2) + 1;
            LOADF(kA, vA, t);
            int i = 0;
            while (i + 2 <= n) {
                LOADF(kB, vB, t + 4);
                asm volatile("s_waitcnt vmcnt(8)" ::: "memory");   // kA/vA landed
                __builtin_amdgcn_sched_barrier(0);
                COMPUTE(kA, vA, t);
                if (i + 2 < n) {
                    LOADF(kA, vA, t + 8);
                    asm volatile("s_waitcnt vmcnt(8)" ::: "memory"); // kB/vB landed
                } else {
                    asm volatile("s_waitcnt vmcnt(0)" ::: "memory");
                }
                __builtin_amdgcn_sched_barrier(0);
                COMPUTE(kB, vB, t + 4);
                t += 8; i += 2;
            }
            if (i < n) {
                asm volatile("s_waitcnt vmcnt(0)" ::: "memory");
                __builtin_amdgcn_sched_barrier(0);
                COMPUTE(kA, vA, t);
            }
        }
    }

    // ---- combine 4 parities (tree via 2 LDS slots); payload = both q-sets ----
    float psumA = (psA[0] + psA[1]) + (psA[2] + psA[3]);
    psumA += __shfl_xor(psumA, 32);
    float psumB = (psB[0] + psB[1]) + (psB[2] + psB[3]);
    psumB += __shfl_xor(psumB, 32);

    if (par & 1) {
        float* s = &ex[par >> 1][lane][0];
#pragma unroll
        for (int dblk = 0; dblk < 2; ++dblk)
#pragma unroll
            for (int g2 = 0; g2 < 4; ++g2) {
                *(float4*)(s + dblk * 16 + g2 * 4) =
                    (float4){oaccA[dblk][4*g2+0], oaccA[dblk][4*g2+1],
                             oaccA[dblk][4*g2+2], oaccA[dblk][4*g2+3]};
                *(float4*)(s + 36 + dblk * 16 + g2 * 4) =
                    (float4){oaccB[dblk][4*g2+0], oaccB[dblk][4*g2+1],
                             oaccB[dblk][4*g2+2], oaccB[dblk][4*g2+3]};
            }
        s[32] = psumA;
        s[68] = psumB;
    }
    __syncthreads();
    if (!(par & 1)) {
        const float* s = &ex[par >> 1][lane][0];
#pragma unroll
        for (int dblk = 0; dblk < 2; ++dblk)
#pragma unroll
            for (int g2 = 0; g2 < 4; ++g2) {
                float4 oa = *(const float4*)(s + dblk * 16 + g2 * 4);
                float4 ob = *(const float4*)(s + 36 + dblk * 16 + g2 * 4);
                oaccA[dblk][4*g2+0] += oa.x; oaccA[dblk][4*g2+1] += oa.y;
                oaccA[dblk][4*g2+2] += oa.z; oaccA[dblk][4*g2+3] += oa.w;
                oaccB[dblk][4*g2+0] += ob.x; oaccB[dblk][4*g2+1] += ob.y;
                oaccB[dblk][4*g2+2] += ob.z; oaccB[dblk][4*g2+3] += ob.w;
            }
        psumA += s[32];
        psumB += s[68];
    }
    __syncthreads();
    if (par == 2) {
        float* s = &ex[0][lane][0];
#pragma unroll
        for (int dblk = 0; dblk < 2; ++dblk)
#pragma unroll
            for (int g2 = 0; g2 < 4; ++g2) {
                *(float4*)(s + dblk * 16 + g2 * 4) =
                    (float4){oaccA[dblk][4*g2+0], oaccA[dblk][4*g2+1],
                             oaccA[dblk][4*g2+2], oaccA[dblk][4*g2+3]};
                *(float4*)(s + 36 + dblk * 16 + g2 * 4) =
                    (float4){oaccB[dblk][4*g2+0], oaccB[dblk][4*g2+1],
                             oaccB[dblk][4*g2+2], oaccB[dblk][4*g2+3]};
            }
        s[32] = psumA;
        s[68] = psumB;
    }
    __syncthreads();
    if (par == 0) {
        const float* s = &ex[0][lane][0];
#pragma unroll
        for (int dblk = 0; dblk < 2; ++dblk)
#pragma unroll
            for (int g2 = 0; g2 < 4; ++g2) {
                float4 oa = *(const float4*)(s + dblk * 16 + g2 * 4);
                float4 ob = *(const float4*)(s + 36 + dblk * 16 + g2 * 4);
                oaccA[dblk][4*g2+0] += oa.x; oaccA[dblk][4*g2+1] += oa.y;
                oaccA[dblk][4*g2+2] += oa.z; oaccA[dblk][4*g2+3] += oa.w;
                oaccB[dblk][4*g2+0] += ob.x; oaccB[dblk][4*g2+1] += ob.y;
                oaccB[dblk][4*g2+2] += ob.z; oaccB[dblk][4*g2+3] += ob.w;
            }
        psumA += s[32];
        psumB += s[68];

        const float invA = 1.f / psumA;
        const float invB = 1.f / psumB;
#pragma unroll
        for (int dblk = 0; dblk < 2; ++dblk)
#pragma unroll
            for (int g2 = 0; g2 < 4; ++g2) {
                float4 oa = {oaccA[dblk][4*g2+0] * invA, oaccA[dblk][4*g2+1] * invA,
                             oaccA[dblk][4*g2+2] * invA, oaccA[dblk][4*g2+3] * invA};
                *(float4*)(Op + (size_t)qrowA * DH + dblk * 32 + g2 * 8 + hi * 4) = oa;
                float4 ob = {oaccB[dblk][4*g2+0] * invB, oaccB[dblk][4*g2+1] * invB,
                             oaccB[dblk][4*g2+2] * invB, oaccB[dblk][4*g2+3] * invB};
                *(float4*)(Op + (size_t)(qrowA + 32) * DH + dblk * 32 + g2 * 8 + hi * 4) = ob;
            }
    }
}

extern "C" void kernel_launch(void* const* d_in, const int* in_sizes, int n_in,
                              void* d_out, int out_size, void* d_ws, size_t ws_size,
                              hipStream_t stream) {
    const float* q = (const float*)d_in[0];
    const float* k = (const float*)d_in[1];
    const float* v = (const float*)d_in[2];
    float* out = (float*)d_out;
    char* W = (char*)d_ws;                    // 32 bh x 64 tiles x 8KB = 16 MB
    alibi_prep_kernel<<<dim3(SQ / 64, 2 * NH, 2), dim3(256), 0, stream>>>(k, v, W);
    const int nblk = 2 * NH * (SQ / 64);      // 1024 blocks (bh, 64-row q-chunk)
    alibi_attn_kernel<<<dim3(nblk), dim3(256), 0, stream>>>(q, W, out);
}